// Round 1
// baseline (1554.349 us; speedup 1.0000x reference)
//
#include <hip/hip_runtime.h>

#define N_NODES 50000
#define N_EDGES 800000
#define DIM 128

// ---------------- degree accumulation ----------------
__global__ __launch_bounds__(256) void degree_kernel(
    const int* __restrict__ src, const int* __restrict__ dst,
    float* __restrict__ deg_out, float* __restrict__ deg_in, int E) {
  int e = blockIdx.x * 256 + threadIdx.x;
  if (e < E) {
    atomicAdd(&deg_out[src[e]], 1.0f);
    atomicAdd(&deg_in[dst[e]], 1.0f);
  }
}

// ---------------- degree -> rsqrt norm (in place) ----------------
__global__ __launch_bounds__(256) void norm_kernel(
    float* __restrict__ deg_out, float* __restrict__ deg_in, int n) {
  int i = blockIdx.x * 256 + threadIdx.x;
  if (i < n) {
    deg_out[i] = rsqrtf(fmaxf(deg_out[i], 1.0f));
    deg_in[i]  = rsqrtf(fmaxf(deg_in[i], 1.0f));
  }
}

// ---------------- edge scatter: agg[dst] += x[src] * norm_src[src] ----------------
// 32 lanes per edge, each lane handles 4 features (float4 gather + 4 atomics).
__global__ __launch_bounds__(256) void scatter_kernel(
    const float4* __restrict__ x4, const int* __restrict__ src,
    const int* __restrict__ dst, const float* __restrict__ norm_src,
    float* __restrict__ agg, int E) {
  int t = threadIdx.x;
  int e = blockIdx.x * 8 + (t >> 5);
  if (e >= E) return;
  int lane = t & 31;
  int s = src[e];
  int d = dst[e];
  float ns = norm_src[s];
  float4 xv = x4[s * 32 + lane];
  float* ap = agg + d * DIM + lane * 4;
  atomicAdd(ap + 0, xv.x * ns);
  atomicAdd(ap + 1, xv.y * ns);
  atomicAdd(ap + 2, xv.z * ns);
  atomicAdd(ap + 3, xv.w * ns);
}

// ---------------- out = relu((agg * norm_dst) @ W + b) ----------------
// Block: 256 threads, 32 rows. W (64KB) + A-tile (16KB) in LDS.
// Thread (col4 = t&31, rowgroup = t>>5) computes 4 rows x 4 cols.
__global__ __launch_bounds__(256) void gemm_relu_kernel(
    const float4* __restrict__ agg4, const float* __restrict__ norm_dst,
    const float4* __restrict__ W4, const float4* __restrict__ b4,
    float4* __restrict__ out4, int n) {
  __shared__ float Wl[DIM * DIM];
  __shared__ float Al[32][DIM];
  int t = threadIdx.x;
  float4* Wl4 = (float4*)Wl;

  // stage W: 128*128 floats = 4096 float4 / 256 threads = 16 each
#pragma unroll
  for (int i = 0; i < 16; ++i) Wl4[t + 256 * i] = W4[t + 256 * i];

  int row0 = blockIdx.x * 32;
  // stage A tile (scaled by norm_dst): 32 rows * 32 float4 = 1024 / 256 = 4 each
#pragma unroll
  for (int ii = 0; ii < 4; ++ii) {
    int i = t + 256 * ii;
    int r = i >> 5, c = i & 31;
    int gr = row0 + r;
    float4 v = make_float4(0.f, 0.f, 0.f, 0.f);
    if (gr < n) {
      v = agg4[gr * 32 + c];
      float nd = norm_dst[gr];
      v.x *= nd; v.y *= nd; v.z *= nd; v.w *= nd;
    }
    ((float4*)Al)[i] = v;
  }
  __syncthreads();

  int col4 = t & 31;        // output col group: cols [col4*4, col4*4+3]
  int r0 = (t >> 5) * 4;    // rows r0..r0+3 within tile

  float4 acc[4];
#pragma unroll
  for (int i = 0; i < 4; ++i) acc[i] = make_float4(0.f, 0.f, 0.f, 0.f);

#pragma unroll 8
  for (int k = 0; k < DIM; k += 4) {
    float4 w0 = Wl4[(k + 0) * 32 + col4];
    float4 w1 = Wl4[(k + 1) * 32 + col4];
    float4 w2 = Wl4[(k + 2) * 32 + col4];
    float4 w3 = Wl4[(k + 3) * 32 + col4];
#pragma unroll
    for (int i = 0; i < 4; ++i) {
      float4 a = *(const float4*)&Al[r0 + i][k];
      acc[i].x = fmaf(a.x, w0.x, fmaf(a.y, w1.x, fmaf(a.z, w2.x, fmaf(a.w, w3.x, acc[i].x))));
      acc[i].y = fmaf(a.x, w0.y, fmaf(a.y, w1.y, fmaf(a.z, w2.y, fmaf(a.w, w3.y, acc[i].y))));
      acc[i].z = fmaf(a.x, w0.z, fmaf(a.y, w1.z, fmaf(a.z, w2.z, fmaf(a.w, w3.z, acc[i].z))));
      acc[i].w = fmaf(a.x, w0.w, fmaf(a.y, w1.w, fmaf(a.z, w2.w, fmaf(a.w, w3.w, acc[i].w))));
    }
  }

  float4 bb = b4[col4];
#pragma unroll
  for (int i = 0; i < 4; ++i) {
    int gr = row0 + r0 + i;
    if (gr < n) {
      float4 o = acc[i];
      o.x = fmaxf(o.x + bb.x, 0.f);
      o.y = fmaxf(o.y + bb.y, 0.f);
      o.z = fmaxf(o.z + bb.z, 0.f);
      o.w = fmaxf(o.w + bb.w, 0.f);
      out4[gr * 32 + col4] = o;
    }
  }
}

extern "C" void kernel_launch(void* const* d_in, const int* in_sizes, int n_in,
                              void* d_out, int out_size, void* d_ws, size_t ws_size,
                              hipStream_t stream) {
  const float* x  = (const float*)d_in[0];
  const int* ei   = (const int*)d_in[1];
  const float* W  = (const float*)d_in[2];
  const float* b  = (const float*)d_in[3];
  float* out      = (float*)d_out;

  const int* src = ei;
  const int* dst = ei + N_EDGES;

  // workspace layout: agg [N*D floats] | deg_out [N] | deg_in [N]
  float* agg     = (float*)d_ws;
  float* deg_out = (float*)((char*)d_ws + (size_t)N_NODES * DIM * sizeof(float));
  float* deg_in  = deg_out + N_NODES;

  size_t zero_bytes = (size_t)N_NODES * DIM * sizeof(float) + 2u * N_NODES * sizeof(float);
  hipMemsetAsync(d_ws, 0, zero_bytes, stream);

  degree_kernel<<<(N_EDGES + 255) / 256, 256, 0, stream>>>(src, dst, deg_out, deg_in, N_EDGES);
  norm_kernel<<<(N_NODES + 255) / 256, 256, 0, stream>>>(deg_out, deg_in, N_NODES);
  scatter_kernel<<<N_EDGES / 8, 256, 0, stream>>>((const float4*)x, src, dst, deg_out, agg, N_EDGES);
  gemm_relu_kernel<<<(N_NODES + 31) / 32, 256, 0, stream>>>(
      (const float4*)agg, deg_in, (const float4*)W, (const float4*)b, (float4*)out, N_NODES);
}

// Round 2
// 319.937 us; speedup vs baseline: 4.8583x; 4.8583x over previous
//
#include <hip/hip_runtime.h>

#define N_NODES 50000
#define N_EDGES 800000
#define DIM 128
#define SCAN_ELEMS 1024
#define SCAN_BLOCKS ((N_NODES + SCAN_ELEMS - 1) / SCAN_ELEMS)  // 49

// ---------------- degree histograms (int atomics) ----------------
__global__ __launch_bounds__(256) void degree_kernel(
    const int* __restrict__ src, const int* __restrict__ dst,
    int* __restrict__ cnt_out, int* __restrict__ cnt_in, int E) {
  int e = blockIdx.x * 256 + threadIdx.x;
  if (e < E) {
    atomicAdd(&cnt_out[src[e]], 1);
    atomicAdd(&cnt_in[dst[e]], 1);
  }
}

// ---------------- counts -> rsqrt norms ----------------
__global__ __launch_bounds__(256) void norm_kernel(
    const int* __restrict__ cnt_out, const int* __restrict__ cnt_in,
    float* __restrict__ norm_out, float* __restrict__ norm_in, int n) {
  int i = blockIdx.x * 256 + threadIdx.x;
  if (i < n) {
    norm_out[i] = rsqrtf(fmaxf((float)cnt_out[i], 1.0f));
    norm_in[i]  = rsqrtf(fmaxf((float)cnt_in[i], 1.0f));
  }
}

// ---------------- scan pass 1: per-block exclusive scan of cnt_in ----------------
__global__ __launch_bounds__(256) void scan1_kernel(
    const int* __restrict__ counts, int* __restrict__ partial,
    int* __restrict__ blockSums, int n) {
  __shared__ int wsum[4];
  int t = threadIdx.x;
  int base = blockIdx.x * SCAN_ELEMS + t * 4;
  int c[4];
#pragma unroll
  for (int i = 0; i < 4; ++i) c[i] = (base + i < n) ? counts[base + i] : 0;
  int s = c[0] + c[1] + c[2] + c[3];
  int lane = t & 63, wid = t >> 6;
  int v = s;
#pragma unroll
  for (int off = 1; off < 64; off <<= 1) {
    int u = __shfl_up(v, off);
    if (lane >= off) v += u;
  }
  if (lane == 63) wsum[wid] = v;
  __syncthreads();
  if (t == 0) {
    int run = 0;
#pragma unroll
    for (int i = 0; i < 4; ++i) { int tmp = wsum[i]; wsum[i] = run; run += tmp; }
    blockSums[blockIdx.x] = run;
  }
  __syncthreads();
  int excl = wsum[wid] + v - s;  // exclusive prefix of this thread within block
  int o0 = excl;
  int o1 = o0 + c[0];
  int o2 = o1 + c[1];
  int o3 = o2 + c[2];
  if (base + 0 < n) partial[base + 0] = o0;
  if (base + 1 < n) partial[base + 1] = o1;
  if (base + 2 < n) partial[base + 2] = o2;
  if (base + 3 < n) partial[base + 3] = o3;
}

// ---------------- scan pass 2: serial scan of 49 block sums ----------------
__global__ void scan2_kernel(int* __restrict__ blockSums, int nb) {
  if (threadIdx.x == 0 && blockIdx.x == 0) {
    int run = 0;
    for (int i = 0; i < nb; ++i) { int t = blockSums[i]; blockSums[i] = run; run += t; }
  }
}

// ---------------- scan pass 3: add block offsets, write offsets + cursor ----------------
__global__ __launch_bounds__(256) void scan3_kernel(
    const int* __restrict__ partial, const int* __restrict__ blockSums,
    int* __restrict__ offsets, int* __restrict__ cursor, int n, int E) {
  int t = threadIdx.x;
  int bo = blockSums[blockIdx.x];
  int base = blockIdx.x * SCAN_ELEMS + t * 4;
#pragma unroll
  for (int i = 0; i < 4; ++i) {
    int idx = base + i;
    if (idx < n) {
      int v = partial[idx] + bo;
      offsets[idx] = v;
      cursor[idx] = v;
    }
  }
  if (blockIdx.x == 0 && t == 0) offsets[n] = E;
}

// ---------------- bucket fill: csr_src grouped by dst ----------------
__global__ __launch_bounds__(256) void fill_kernel(
    const int* __restrict__ src, const int* __restrict__ dst,
    int* __restrict__ cursor, int* __restrict__ csr_src, int E) {
  int e = blockIdx.x * 256 + threadIdx.x;
  if (e < E) {
    int pos = atomicAdd(&cursor[dst[e]], 1);
    csr_src[pos] = src[e];
  }
}

// ---------------- y = x @ W (fp32, LDS-tiled) ----------------
__global__ __launch_bounds__(256) void gemm_kernel(
    const float4* __restrict__ x4, const float4* __restrict__ W4,
    float4* __restrict__ y4, int n) {
  __shared__ float Wl[DIM * DIM];
  __shared__ float Al[32][DIM];
  int t = threadIdx.x;
  float4* Wl4 = (float4*)Wl;

#pragma unroll
  for (int i = 0; i < 16; ++i) Wl4[t + 256 * i] = W4[t + 256 * i];

  int row0 = blockIdx.x * 32;
#pragma unroll
  for (int ii = 0; ii < 4; ++ii) {
    int i = t + 256 * ii;
    int r = i >> 5, c = i & 31;
    int gr = row0 + r;
    float4 v = make_float4(0.f, 0.f, 0.f, 0.f);
    if (gr < n) v = x4[gr * 32 + c];
    ((float4*)Al)[i] = v;
  }
  __syncthreads();

  int col4 = t & 31;
  int r0 = (t >> 5) * 4;

  float4 acc[4];
#pragma unroll
  for (int i = 0; i < 4; ++i) acc[i] = make_float4(0.f, 0.f, 0.f, 0.f);

#pragma unroll 8
  for (int k = 0; k < DIM; k += 4) {
    float4 w0 = Wl4[(k + 0) * 32 + col4];
    float4 w1 = Wl4[(k + 1) * 32 + col4];
    float4 w2 = Wl4[(k + 2) * 32 + col4];
    float4 w3 = Wl4[(k + 3) * 32 + col4];
#pragma unroll
    for (int i = 0; i < 4; ++i) {
      float4 a = *(const float4*)&Al[r0 + i][k];
      acc[i].x = fmaf(a.x, w0.x, fmaf(a.y, w1.x, fmaf(a.z, w2.x, fmaf(a.w, w3.x, acc[i].x))));
      acc[i].y = fmaf(a.x, w0.y, fmaf(a.y, w1.y, fmaf(a.z, w2.y, fmaf(a.w, w3.y, acc[i].y))));
      acc[i].z = fmaf(a.x, w0.z, fmaf(a.y, w1.z, fmaf(a.z, w2.z, fmaf(a.w, w3.z, acc[i].z))));
      acc[i].w = fmaf(a.x, w0.w, fmaf(a.y, w1.w, fmaf(a.z, w2.w, fmaf(a.w, w3.w, acc[i].w))));
    }
  }

#pragma unroll
  for (int i = 0; i < 4; ++i) {
    int gr = row0 + r0 + i;
    if (gr < n) y4[gr * 32 + col4] = acc[i];
  }
}

// ---------------- out[d] = relu(norm_in[d] * sum_{e in seg(d)} norm_out[s]*y[s] + b) ----------------
// one wave (64 lanes) per node; lane owns 2 features (float2)
__global__ __launch_bounds__(256) void aggregate_kernel(
    const float2* __restrict__ y2, const int* __restrict__ csr_src,
    const int* __restrict__ offsets, const float* __restrict__ norm_out,
    const float* __restrict__ norm_in, const float2* __restrict__ b2,
    float2* __restrict__ out2, int n) {
  int t = threadIdx.x;
  int node = blockIdx.x * 4 + (t >> 6);
  if (node >= n) return;
  int lane = t & 63;
  int beg = offsets[node], end = offsets[node + 1];
  float2 acc = make_float2(0.f, 0.f);
  for (int j = beg; j < end; ++j) {
    int s = csr_src[j];
    float ns = norm_out[s];
    float2 v = y2[(size_t)s * 64 + lane];
    acc.x = fmaf(v.x, ns, acc.x);
    acc.y = fmaf(v.y, ns, acc.y);
  }
  float ni = norm_in[node];
  float2 bb = b2[lane];
  float2 o;
  o.x = fmaxf(fmaf(acc.x, ni, bb.x), 0.f);
  o.y = fmaxf(fmaf(acc.y, ni, bb.y), 0.f);
  out2[(size_t)node * 64 + lane] = o;
}

extern "C" void kernel_launch(void* const* d_in, const int* in_sizes, int n_in,
                              void* d_out, int out_size, void* d_ws, size_t ws_size,
                              hipStream_t stream) {
  const float* x  = (const float*)d_in[0];
  const int* ei   = (const int*)d_in[1];
  const float* W  = (const float*)d_in[2];
  const float* b  = (const float*)d_in[3];
  float* out      = (float*)d_out;

  const int* src = ei;
  const int* dst = ei + N_EDGES;

  // workspace layout
  char* p = (char*)d_ws;
  float* y       = (float*)p;              p += (size_t)N_NODES * DIM * sizeof(float);   // 25.6 MB
  int* cnt_out   = (int*)p;                p += (size_t)N_NODES * sizeof(int);
  int* cnt_in    = (int*)p;                p += (size_t)N_NODES * sizeof(int);
  float* norm_out= (float*)p;              p += (size_t)N_NODES * sizeof(float);
  float* norm_in = (float*)p;              p += (size_t)N_NODES * sizeof(float);
  int* offsets   = (int*)p;                p += (size_t)(N_NODES + 1) * sizeof(int);
  int* cursor    = (int*)p;                p += (size_t)N_NODES * sizeof(int);
  int* partial   = (int*)p;                p += (size_t)N_NODES * sizeof(int);
  int* blockSums = (int*)p;                p += 64 * sizeof(int);
  int* csr_src   = (int*)p;                p += (size_t)N_EDGES * sizeof(int);           // 3.2 MB

  // zero only the histograms
  hipMemsetAsync(cnt_out, 0, 2u * N_NODES * sizeof(int), stream);

  degree_kernel<<<(N_EDGES + 255) / 256, 256, 0, stream>>>(src, dst, cnt_out, cnt_in, N_EDGES);
  norm_kernel<<<(N_NODES + 255) / 256, 256, 0, stream>>>(cnt_out, cnt_in, norm_out, norm_in, N_NODES);
  scan1_kernel<<<SCAN_BLOCKS, 256, 0, stream>>>(cnt_in, partial, blockSums, N_NODES);
  scan2_kernel<<<1, 64, 0, stream>>>(blockSums, SCAN_BLOCKS);
  scan3_kernel<<<SCAN_BLOCKS, 256, 0, stream>>>(partial, blockSums, offsets, cursor, N_NODES, N_EDGES);
  fill_kernel<<<(N_EDGES + 255) / 256, 256, 0, stream>>>(src, dst, cursor, csr_src, N_EDGES);
  gemm_kernel<<<(N_NODES + 31) / 32, 256, 0, stream>>>(
      (const float4*)x, (const float4*)W, (float4*)y, N_NODES);
  aggregate_kernel<<<(N_NODES + 3) / 4, 256, 0, stream>>>(
      (const float2*)y, csr_src, offsets, norm_out, norm_in,
      (const float2*)b, (float2*)out, N_NODES);
}

// Round 4
// 297.611 us; speedup vs baseline: 5.2228x; 1.0750x over previous
//
#include <hip/hip_runtime.h>

#define N_NODES 50000
#define N_EDGES 800000
#define DIM 128
#define SCAN_ELEMS 1024
#define SCAN_BLOCKS ((N_NODES + SCAN_ELEMS - 1) / SCAN_ELEMS)  // 49

typedef unsigned int uint;

__device__ __forceinline__ uint bf16pair(float a, float b) {
  uint ua = __float_as_uint(a); ua = (ua + 0x7FFFu + ((ua >> 16) & 1u)) >> 16;
  uint ub = __float_as_uint(b); ub = (ub + 0x7FFFu + ((ub >> 16) & 1u)) >> 16;
  return ua | (ub << 16);
}

// ---------------- degree histograms (int atomics) ----------------
__global__ __launch_bounds__(256) void degree_kernel(
    const int* __restrict__ src, const int* __restrict__ dst,
    int* __restrict__ cnt_out, int* __restrict__ cnt_in, int E) {
  int e = blockIdx.x * 256 + threadIdx.x;
  if (e < E) {
    atomicAdd(&cnt_out[src[e]], 1);
    atomicAdd(&cnt_in[dst[e]], 1);
  }
}

// ---------------- counts -> rsqrt norms ----------------
__global__ __launch_bounds__(256) void norm_kernel(
    const int* __restrict__ cnt_out, const int* __restrict__ cnt_in,
    float* __restrict__ norm_out, float* __restrict__ norm_in, int n) {
  int i = blockIdx.x * 256 + threadIdx.x;
  if (i < n) {
    norm_out[i] = rsqrtf(fmaxf((float)cnt_out[i], 1.0f));
    norm_in[i]  = rsqrtf(fmaxf((float)cnt_in[i], 1.0f));
  }
}

// ---------------- scan pass 1: per-block exclusive scan of cnt_in ----------------
__global__ __launch_bounds__(256) void scan1_kernel(
    const int* __restrict__ counts, int* __restrict__ partial,
    int* __restrict__ blockSums, int n) {
  __shared__ int wsum[4];
  int t = threadIdx.x;
  int base = blockIdx.x * SCAN_ELEMS + t * 4;
  int c[4];
#pragma unroll
  for (int i = 0; i < 4; ++i) c[i] = (base + i < n) ? counts[base + i] : 0;
  int s = c[0] + c[1] + c[2] + c[3];
  int lane = t & 63, wid = t >> 6;
  int v = s;
#pragma unroll
  for (int off = 1; off < 64; off <<= 1) {
    int u = __shfl_up(v, off);
    if (lane >= off) v += u;
  }
  if (lane == 63) wsum[wid] = v;
  __syncthreads();
  if (t == 0) {
    int run = 0;
#pragma unroll
    for (int i = 0; i < 4; ++i) { int tmp = wsum[i]; wsum[i] = run; run += tmp; }
    blockSums[blockIdx.x] = run;
  }
  __syncthreads();
  int excl = wsum[wid] + v - s;
  int o0 = excl;
  int o1 = o0 + c[0];
  int o2 = o1 + c[1];
  int o3 = o2 + c[2];
  if (base + 0 < n) partial[base + 0] = o0;
  if (base + 1 < n) partial[base + 1] = o1;
  if (base + 2 < n) partial[base + 2] = o2;
  if (base + 3 < n) partial[base + 3] = o3;
}

// ---------------- scan pass 2: serial scan of 49 block sums ----------------
__global__ void scan2_kernel(int* __restrict__ blockSums, int nb) {
  if (threadIdx.x == 0 && blockIdx.x == 0) {
    int run = 0;
    for (int i = 0; i < nb; ++i) { int t = blockSums[i]; blockSums[i] = run; run += t; }
  }
}

// ---------------- scan pass 3: add block offsets, write offsets + cursor ----------------
__global__ __launch_bounds__(256) void scan3_kernel(
    const int* __restrict__ partial, const int* __restrict__ blockSums,
    int* __restrict__ offsets, int* __restrict__ cursor, int n, int E) {
  int t = threadIdx.x;
  int bo = blockSums[blockIdx.x];
  int base = blockIdx.x * SCAN_ELEMS + t * 4;
#pragma unroll
  for (int i = 0; i < 4; ++i) {
    int idx = base + i;
    if (idx < n) {
      int v = partial[idx] + bo;
      offsets[idx] = v;
      cursor[idx] = v;
    }
  }
  if (blockIdx.x == 0 && t == 0) offsets[n] = E;
}

// ---------------- bucket fill: csr_src grouped by dst ----------------
__global__ __launch_bounds__(256) void fill_kernel(
    const int* __restrict__ src, const int* __restrict__ dst,
    int* __restrict__ cursor, int* __restrict__ csr_src, int E) {
  int e = blockIdx.x * 256 + threadIdx.x;
  if (e < E) {
    int pos = atomicAdd(&cursor[dst[e]], 1);
    csr_src[pos] = src[e];
  }
}

// ---------------- y_bf16[r] = norm_out[r] * (x[r] @ W)  (fp32 compute, bf16 store) ----------------
__global__ __launch_bounds__(256) void gemm_kernel(
    const float4* __restrict__ x4, const float4* __restrict__ W4,
    const float* __restrict__ norm_out, uint2* __restrict__ yb2, int n) {
  __shared__ float Wl[DIM * DIM];
  __shared__ float Al[32][DIM];
  int t = threadIdx.x;
  float4* Wl4 = (float4*)Wl;

#pragma unroll
  for (int i = 0; i < 16; ++i) Wl4[t + 256 * i] = W4[t + 256 * i];

  int row0 = blockIdx.x * 32;
#pragma unroll
  for (int ii = 0; ii < 4; ++ii) {
    int i = t + 256 * ii;
    int r = i >> 5, c = i & 31;
    int gr = row0 + r;
    float4 v = make_float4(0.f, 0.f, 0.f, 0.f);
    if (gr < n) v = x4[gr * 32 + c];
    ((float4*)Al)[i] = v;
  }
  __syncthreads();

  int col4 = t & 31;
  int r0 = (t >> 5) * 4;

  float4 acc[4];
#pragma unroll
  for (int i = 0; i < 4; ++i) acc[i] = make_float4(0.f, 0.f, 0.f, 0.f);

#pragma unroll 8
  for (int k = 0; k < DIM; k += 4) {
    float4 w0 = Wl4[(k + 0) * 32 + col4];
    float4 w1 = Wl4[(k + 1) * 32 + col4];
    float4 w2 = Wl4[(k + 2) * 32 + col4];
    float4 w3 = Wl4[(k + 3) * 32 + col4];
#pragma unroll
    for (int i = 0; i < 4; ++i) {
      float4 a = *(const float4*)&Al[r0 + i][k];
      acc[i].x = fmaf(a.x, w0.x, fmaf(a.y, w1.x, fmaf(a.z, w2.x, fmaf(a.w, w3.x, acc[i].x))));
      acc[i].y = fmaf(a.x, w0.y, fmaf(a.y, w1.y, fmaf(a.z, w2.y, fmaf(a.w, w3.y, acc[i].y))));
      acc[i].z = fmaf(a.x, w0.z, fmaf(a.y, w1.z, fmaf(a.z, w2.z, fmaf(a.w, w3.z, acc[i].z))));
      acc[i].w = fmaf(a.x, w0.w, fmaf(a.y, w1.w, fmaf(a.z, w2.w, fmaf(a.w, w3.w, acc[i].w))));
    }
  }

#pragma unroll
  for (int i = 0; i < 4; ++i) {
    int gr = row0 + r0 + i;
    if (gr < n) {
      float ns = norm_out[gr];
      float4 o = acc[i];
      uint2 packed;
      packed.x = bf16pair(o.x * ns, o.y * ns);
      packed.y = bf16pair(o.z * ns, o.w * ns);
      yb2[(size_t)gr * 32 + col4] = packed;
    }
  }
}

// ---------------- out[d] = relu(norm_in[d] * sum_{e in seg(d)} ybf16[src(e)] + b) ----------------
// one wave per node; lane owns 2 features (1 dword of 2 bf16); 4-deep ILP unroll
__global__ __launch_bounds__(256) void aggregate_kernel(
    const uint* __restrict__ yb, const int* __restrict__ csr_src,
    const int* __restrict__ offsets, const float* __restrict__ norm_in,
    const float2* __restrict__ b2, float2* __restrict__ out2, int n) {
  int t = threadIdx.x;
  int node = blockIdx.x * 4 + (t >> 6);
  if (node >= n) return;
  int lane = t & 63;
  int beg = offsets[node], end = offsets[node + 1];

  float ax0 = 0.f, ay0 = 0.f, ax1 = 0.f, ay1 = 0.f;
  float ax2 = 0.f, ay2 = 0.f, ax3 = 0.f, ay3 = 0.f;
  int j = beg;
  for (; j + 4 <= end; j += 4) {
    int s0 = csr_src[j + 0];
    int s1 = csr_src[j + 1];
    int s2 = csr_src[j + 2];
    int s3 = csr_src[j + 3];
    uint u0 = yb[(size_t)s0 * 64 + lane];
    uint u1 = yb[(size_t)s1 * 64 + lane];
    uint u2 = yb[(size_t)s2 * 64 + lane];
    uint u3 = yb[(size_t)s3 * 64 + lane];
    ax0 += __uint_as_float(u0 << 16);
    ay0 += __uint_as_float(u0 & 0xFFFF0000u);
    ax1 += __uint_as_float(u1 << 16);
    ay1 += __uint_as_float(u1 & 0xFFFF0000u);
    ax2 += __uint_as_float(u2 << 16);
    ay2 += __uint_as_float(u2 & 0xFFFF0000u);
    ax3 += __uint_as_float(u3 << 16);
    ay3 += __uint_as_float(u3 & 0xFFFF0000u);
  }
  for (; j < end; ++j) {
    int s0 = csr_src[j];
    uint u0 = yb[(size_t)s0 * 64 + lane];
    ax0 += __uint_as_float(u0 << 16);
    ay0 += __uint_as_float(u0 & 0xFFFF0000u);
  }
  float sx = (ax0 + ax1) + (ax2 + ax3);
  float sy = (ay0 + ay1) + (ay2 + ay3);

  float ni = norm_in[node];
  float2 bb = b2[lane];
  float2 o;
  o.x = fmaxf(fmaf(sx, ni, bb.x), 0.f);
  o.y = fmaxf(fmaf(sy, ni, bb.y), 0.f);
  out2[(size_t)node * 64 + lane] = o;
}

extern "C" void kernel_launch(void* const* d_in, const int* in_sizes, int n_in,
                              void* d_out, int out_size, void* d_ws, size_t ws_size,
                              hipStream_t stream) {
  const float* x  = (const float*)d_in[0];
  const int* ei   = (const int*)d_in[1];
  const float* W  = (const float*)d_in[2];
  const float* b  = (const float*)d_in[3];
  float* out      = (float*)d_out;

  const int* src = ei;
  const int* dst = ei + N_EDGES;

  // workspace layout
  char* p = (char*)d_ws;
  uint* yb       = (uint*)p;               p += (size_t)N_NODES * DIM * sizeof(unsigned short); // 12.8 MB bf16
  int* cnt_out   = (int*)p;                p += (size_t)N_NODES * sizeof(int);
  int* cnt_in    = (int*)p;                p += (size_t)N_NODES * sizeof(int);
  float* norm_out= (float*)p;              p += (size_t)N_NODES * sizeof(float);
  float* norm_in = (float*)p;              p += (size_t)N_NODES * sizeof(float);
  int* offsets   = (int*)p;                p += (size_t)(N_NODES + 1) * sizeof(int);
  int* cursor    = (int*)p;                p += (size_t)N_NODES * sizeof(int);
  int* partial   = (int*)p;                p += (size_t)N_NODES * sizeof(int);
  int* blockSums = (int*)p;                p += 64 * sizeof(int);
  int* csr_src   = (int*)p;                p += (size_t)N_EDGES * sizeof(int);                  // 3.2 MB

  // zero only the histograms
  hipMemsetAsync(cnt_out, 0, 2u * N_NODES * sizeof(int), stream);

  degree_kernel<<<(N_EDGES + 255) / 256, 256, 0, stream>>>(src, dst, cnt_out, cnt_in, N_EDGES);
  norm_kernel<<<(N_NODES + 255) / 256, 256, 0, stream>>>(cnt_out, cnt_in, norm_out, norm_in, N_NODES);
  gemm_kernel<<<(N_NODES + 31) / 32, 256, 0, stream>>>(
      (const float4*)x, (const float4*)W, norm_out, (uint2*)yb, N_NODES);
  scan1_kernel<<<SCAN_BLOCKS, 256, 0, stream>>>(cnt_in, partial, blockSums, N_NODES);
  scan2_kernel<<<1, 64, 0, stream>>>(blockSums, SCAN_BLOCKS);
  scan3_kernel<<<SCAN_BLOCKS, 256, 0, stream>>>(partial, blockSums, offsets, cursor, N_NODES, N_EDGES);
  fill_kernel<<<(N_EDGES + 255) / 256, 256, 0, stream>>>(src, dst, cursor, csr_src, N_EDGES);
  aggregate_kernel<<<(N_NODES + 3) / 4, 256, 0, stream>>>(
      yb, csr_src, offsets, norm_in, (const float2*)b, (float2*)out, N_NODES);
}

// Round 5
// 283.741 us; speedup vs baseline: 5.4781x; 1.0489x over previous
//
#include <hip/hip_runtime.h>

#define N_NODES 50000
#define N_EDGES 800000
#define DIM 128
#define PAD 16  // one 64B cacheline per counter
#define SCAN_ELEMS 1024
#define SCAN_BLOCKS ((N_NODES + SCAN_ELEMS - 1) / SCAN_ELEMS)  // 49

typedef unsigned int uint;

__device__ __forceinline__ uint bf16pair(float a, float b) {
  uint ua = __float_as_uint(a); ua = (ua + 0x7FFFu + ((ua >> 16) & 1u)) >> 16;
  uint ub = __float_as_uint(b); ub = (ub + 0x7FFFu + ((ub >> 16) & 1u)) >> 16;
  return ua | (ub << 16);
}

// ---------------- degree histograms (padded counters, 4 edges/thread) ----------------
__global__ __launch_bounds__(256) void degree_kernel(
    const int4* __restrict__ src4, const int4* __restrict__ dst4,
    int* __restrict__ cnt_out, int* __restrict__ cnt_in, int E4) {
  int i = blockIdx.x * 256 + threadIdx.x;
  if (i < E4) {
    int4 s = src4[i];
    int4 d = dst4[i];
    atomicAdd(&cnt_out[s.x * PAD], 1);
    atomicAdd(&cnt_out[s.y * PAD], 1);
    atomicAdd(&cnt_out[s.z * PAD], 1);
    atomicAdd(&cnt_out[s.w * PAD], 1);
    atomicAdd(&cnt_in[d.x * PAD], 1);
    atomicAdd(&cnt_in[d.y * PAD], 1);
    atomicAdd(&cnt_in[d.z * PAD], 1);
    atomicAdd(&cnt_in[d.w * PAD], 1);
  }
}

// ---------------- padded counts -> rsqrt norms ----------------
__global__ __launch_bounds__(256) void norm_kernel(
    const int* __restrict__ cnt_out, const int* __restrict__ cnt_in,
    float* __restrict__ norm_out, float* __restrict__ norm_in, int n) {
  int i = blockIdx.x * 256 + threadIdx.x;
  if (i < n) {
    norm_out[i] = rsqrtf(fmaxf((float)cnt_out[i * PAD], 1.0f));
    norm_in[i]  = rsqrtf(fmaxf((float)cnt_in[i * PAD], 1.0f));
  }
}

// ---------------- scan pass 1: per-block exclusive scan of padded cnt_in ----------------
__global__ __launch_bounds__(256) void scan1_kernel(
    const int* __restrict__ counts, int* __restrict__ partial,
    int* __restrict__ blockSums, int n) {
  __shared__ int wsum[4];
  int t = threadIdx.x;
  int base = blockIdx.x * SCAN_ELEMS + t * 4;
  int c[4];
#pragma unroll
  for (int i = 0; i < 4; ++i) c[i] = (base + i < n) ? counts[(base + i) * PAD] : 0;
  int s = c[0] + c[1] + c[2] + c[3];
  int lane = t & 63, wid = t >> 6;
  int v = s;
#pragma unroll
  for (int off = 1; off < 64; off <<= 1) {
    int u = __shfl_up(v, off);
    if (lane >= off) v += u;
  }
  if (lane == 63) wsum[wid] = v;
  __syncthreads();
  if (t == 0) {
    int run = 0;
#pragma unroll
    for (int i = 0; i < 4; ++i) { int tmp = wsum[i]; wsum[i] = run; run += tmp; }
    blockSums[blockIdx.x] = run;
  }
  __syncthreads();
  int excl = wsum[wid] + v - s;
  int o0 = excl;
  int o1 = o0 + c[0];
  int o2 = o1 + c[1];
  int o3 = o2 + c[2];
  if (base + 0 < n) partial[base + 0] = o0;
  if (base + 1 < n) partial[base + 1] = o1;
  if (base + 2 < n) partial[base + 2] = o2;
  if (base + 3 < n) partial[base + 3] = o3;
}

// ---------------- scan pass 2: serial scan of 49 block sums ----------------
__global__ void scan2_kernel(int* __restrict__ blockSums, int nb) {
  if (threadIdx.x == 0 && blockIdx.x == 0) {
    int run = 0;
    for (int i = 0; i < nb; ++i) { int t = blockSums[i]; blockSums[i] = run; run += t; }
  }
}

// ---------------- scan pass 3: offsets (dense) + cursor (padded) ----------------
__global__ __launch_bounds__(256) void scan3_kernel(
    const int* __restrict__ partial, const int* __restrict__ blockSums,
    int* __restrict__ offsets, int* __restrict__ cursor, int n, int E) {
  int t = threadIdx.x;
  int bo = blockSums[blockIdx.x];
  int base = blockIdx.x * SCAN_ELEMS + t * 4;
#pragma unroll
  for (int i = 0; i < 4; ++i) {
    int idx = base + i;
    if (idx < n) {
      int v = partial[idx] + bo;
      offsets[idx] = v;
      cursor[idx * PAD] = v;
    }
  }
  if (blockIdx.x == 0 && t == 0) offsets[n] = E;
}

// ---------------- bucket fill: 4 edges/thread, padded cursor ----------------
__global__ __launch_bounds__(256) void fill_kernel(
    const int4* __restrict__ src4, const int4* __restrict__ dst4,
    int* __restrict__ cursor, int* __restrict__ csr_src, int E4) {
  int i = blockIdx.x * 256 + threadIdx.x;
  if (i < E4) {
    int4 s = src4[i];
    int4 d = dst4[i];
    int p0 = atomicAdd(&cursor[d.x * PAD], 1);
    int p1 = atomicAdd(&cursor[d.y * PAD], 1);
    int p2 = atomicAdd(&cursor[d.z * PAD], 1);
    int p3 = atomicAdd(&cursor[d.w * PAD], 1);
    csr_src[p0] = s.x;
    csr_src[p1] = s.y;
    csr_src[p2] = s.z;
    csr_src[p3] = s.w;
  }
}

// ---------------- y_bf16[r] = norm_out[r] * (x[r] @ W) ----------------
// 64 rows/block; W (64KB) in LDS, A direct from global (half-wave broadcast).
// Thread (col4 = t&31, rowgrp = t>>5) computes 8 rows x 4 cols.
__global__ __launch_bounds__(256) void gemm_kernel(
    const float4* __restrict__ x4, const float4* __restrict__ W4,
    const float* __restrict__ norm_out, uint2* __restrict__ yb2, int n) {
  __shared__ float4 Wl4[DIM * 32];  // Wl4[k*32 + c4], 64KB
  int t = threadIdx.x;
#pragma unroll
  for (int i = 0; i < 16; ++i) Wl4[t + 256 * i] = W4[t + 256 * i];
  __syncthreads();

  int col4 = t & 31;
  int rg = t >> 5;                     // 0..7
  int row0 = blockIdx.x * 64 + rg * 8; // 8 consecutive rows per thread

  float4 acc[8];
#pragma unroll
  for (int i = 0; i < 8; ++i) acc[i] = make_float4(0.f, 0.f, 0.f, 0.f);

#pragma unroll 2
  for (int kc = 0; kc < 32; ++kc) {    // k-chunk of 4 floats
    float4 w0 = Wl4[(4 * kc + 0) * 32 + col4];
    float4 w1 = Wl4[(4 * kc + 1) * 32 + col4];
    float4 w2 = Wl4[(4 * kc + 2) * 32 + col4];
    float4 w3 = Wl4[(4 * kc + 3) * 32 + col4];
#pragma unroll
    for (int i = 0; i < 8; ++i) {
      int gr = row0 + i;
      int cr = gr < n ? gr : n - 1;    // clamp; OOB rows discarded at store
      float4 a = x4[(size_t)cr * 32 + kc];
      acc[i].x = fmaf(a.x, w0.x, fmaf(a.y, w1.x, fmaf(a.z, w2.x, fmaf(a.w, w3.x, acc[i].x))));
      acc[i].y = fmaf(a.x, w0.y, fmaf(a.y, w1.y, fmaf(a.z, w2.y, fmaf(a.w, w3.y, acc[i].y))));
      acc[i].z = fmaf(a.x, w0.z, fmaf(a.y, w1.z, fmaf(a.z, w2.z, fmaf(a.w, w3.z, acc[i].z))));
      acc[i].w = fmaf(a.x, w0.w, fmaf(a.y, w1.w, fmaf(a.z, w2.w, fmaf(a.w, w3.w, acc[i].w))));
    }
  }

#pragma unroll
  for (int i = 0; i < 8; ++i) {
    int gr = row0 + i;
    if (gr < n) {
      float ns = norm_out[gr];
      float4 o = acc[i];
      uint2 packed;
      packed.x = bf16pair(o.x * ns, o.y * ns);
      packed.y = bf16pair(o.z * ns, o.w * ns);
      yb2[(size_t)gr * 32 + col4] = packed;
    }
  }
}

// ---------------- out[d] = relu(norm_in[d] * sum_seg ybf16[src] + b) ----------------
__global__ __launch_bounds__(256) void aggregate_kernel(
    const uint* __restrict__ yb, const int* __restrict__ csr_src,
    const int* __restrict__ offsets, const float* __restrict__ norm_in,
    const float2* __restrict__ b2, float2* __restrict__ out2, int n) {
  int t = threadIdx.x;
  int node = blockIdx.x * 4 + (t >> 6);
  if (node >= n) return;
  int lane = t & 63;
  int beg = offsets[node], end = offsets[node + 1];

  float ax0 = 0.f, ay0 = 0.f, ax1 = 0.f, ay1 = 0.f;
  float ax2 = 0.f, ay2 = 0.f, ax3 = 0.f, ay3 = 0.f;
  int j = beg;
  for (; j + 4 <= end; j += 4) {
    int s0 = csr_src[j + 0];
    int s1 = csr_src[j + 1];
    int s2 = csr_src[j + 2];
    int s3 = csr_src[j + 3];
    uint u0 = yb[(size_t)s0 * 64 + lane];
    uint u1 = yb[(size_t)s1 * 64 + lane];
    uint u2 = yb[(size_t)s2 * 64 + lane];
    uint u3 = yb[(size_t)s3 * 64 + lane];
    ax0 += __uint_as_float(u0 << 16);
    ay0 += __uint_as_float(u0 & 0xFFFF0000u);
    ax1 += __uint_as_float(u1 << 16);
    ay1 += __uint_as_float(u1 & 0xFFFF0000u);
    ax2 += __uint_as_float(u2 << 16);
    ay2 += __uint_as_float(u2 & 0xFFFF0000u);
    ax3 += __uint_as_float(u3 << 16);
    ay3 += __uint_as_float(u3 & 0xFFFF0000u);
  }
  for (; j < end; ++j) {
    int s0 = csr_src[j];
    uint u0 = yb[(size_t)s0 * 64 + lane];
    ax0 += __uint_as_float(u0 << 16);
    ay0 += __uint_as_float(u0 & 0xFFFF0000u);
  }
  float sx = (ax0 + ax1) + (ax2 + ax3);
  float sy = (ay0 + ay1) + (ay2 + ay3);

  float ni = norm_in[node];
  float2 bb = b2[lane];
  float2 o;
  o.x = fmaxf(fmaf(sx, ni, bb.x), 0.f);
  o.y = fmaxf(fmaf(sy, ni, bb.y), 0.f);
  out2[(size_t)node * 64 + lane] = o;
}

extern "C" void kernel_launch(void* const* d_in, const int* in_sizes, int n_in,
                              void* d_out, int out_size, void* d_ws, size_t ws_size,
                              hipStream_t stream) {
  const float* x  = (const float*)d_in[0];
  const int* ei   = (const int*)d_in[1];
  const float* W  = (const float*)d_in[2];
  const float* b  = (const float*)d_in[3];
  float* out      = (float*)d_out;

  const int* src = ei;
  const int* dst = ei + N_EDGES;

  // workspace layout
  char* p = (char*)d_ws;
  uint* yb       = (uint*)p;   p += (size_t)N_NODES * DIM * sizeof(unsigned short);   // 12.8 MB
  int* cnt_out   = (int*)p;    p += (size_t)N_NODES * PAD * sizeof(int);              // 3.2 MB
  int* cnt_in    = (int*)p;    p += (size_t)N_NODES * PAD * sizeof(int);              // 3.2 MB
  int* cursor    = (int*)p;    p += (size_t)N_NODES * PAD * sizeof(int);              // 3.2 MB
  float* norm_out= (float*)p;  p += (size_t)N_NODES * sizeof(float);
  float* norm_in = (float*)p;  p += (size_t)N_NODES * sizeof(float);
  int* offsets   = (int*)p;    p += (size_t)(N_NODES + 1) * sizeof(int);
  int* partial   = (int*)p;    p += (size_t)N_NODES * sizeof(int);
  int* blockSums = (int*)p;    p += 64 * sizeof(int);
  int* csr_src   = (int*)p;    p += (size_t)N_EDGES * sizeof(int);                    // 3.2 MB

  // zero the two histogram arrays (adjacent)
  hipMemsetAsync(cnt_out, 0, 2u * (size_t)N_NODES * PAD * sizeof(int), stream);

  const int E4 = N_EDGES / 4;             // 200000
  const int eb = (E4 + 255) / 256;        // 782

  degree_kernel<<<eb, 256, 0, stream>>>((const int4*)src, (const int4*)dst, cnt_out, cnt_in, E4);
  norm_kernel<<<(N_NODES + 255) / 256, 256, 0, stream>>>(cnt_out, cnt_in, norm_out, norm_in, N_NODES);
  gemm_kernel<<<(N_NODES + 63) / 64, 256, 0, stream>>>(
      (const float4*)x, (const float4*)W, norm_out, (uint2*)yb, N_NODES);
  scan1_kernel<<<SCAN_BLOCKS, 256, 0, stream>>>(cnt_in, partial, blockSums, N_NODES);
  scan2_kernel<<<1, 64, 0, stream>>>(blockSums, SCAN_BLOCKS);
  scan3_kernel<<<SCAN_BLOCKS, 256, 0, stream>>>(partial, blockSums, offsets, cursor, N_NODES, N_EDGES);
  fill_kernel<<<eb, 256, 0, stream>>>((const int4*)src, (const int4*)dst, cursor, csr_src, E4);
  aggregate_kernel<<<(N_NODES + 3) / 4, 256, 0, stream>>>(
      yb, csr_src, offsets, norm_in, (const float2*)b, (float2*)out, N_NODES);
}